// Round 11
// baseline (43.973 us; speedup 1.0000x reference)
//
#include <hip/hip_runtime.h>

// One-way Chamfer (L1, K=1): out[0] = mean_i min_j ||x_i - y_j||_1 ; out[1..N] = 0
// N = M = 16384, D = 3, fp32.
//
// R11: chamfer is near the m07-calibrated VALU floor (~27us); remaining cost
// is plumbing. Changes vs R10: (1) RB=1/YSEG=512 halves prologue x-reload
// redundancy (msplit 64->32), 6-load prologue; (2) partial-buffer round-trip
// (4MB store + strided re-read + 2 extra dispatches) replaced by 512K uint
// atomicMins into 64KB minbits (8x fewer than R8 where the drain showed) +
// one finalize kernel (zeros in parallel, block 0 sums minbits). Inner loop
// unchanged: y broadcast via s_load_dwordx16/x8 double-buffer on the scalar
// pipe, exactly 11 VALU instr / 2 pairs (abs as src-mods, v_min3_f32).

#define TPB 256
#define YSEG 512
#define NITER (YSEG / 16)          // 32 unroll-2 iterations

typedef float sf16 __attribute__((ext_vector_type(16)));
typedef float sf8  __attribute__((ext_vector_type(8)));

// issue the 24-dword (8 y-point) group load; byte offsets are string literals
#define SLOAD24(B16, B8, PTR, O16, O8)                                     \
  asm volatile("s_load_dwordx16 %0, %2, " O16 "\n\t"                       \
               "s_load_dwordx8  %1, %2, " O8                               \
               : "=s"(B16), "=s"(B8) : "s"(PTR));

// wait for ALL outstanding SMEM; "+s" makes consumers of the buffers
// data-dependent on this asm so reads can't be hoisted above the wait
#define SWAIT(B16, B8)                                                     \
  asm volatile("s_waitcnt lgkmcnt(0)" : "+s"(B16), "+s"(B8));

// MR = min3(MR, |a-y0|_1, |a-y1|_1); y components are SGPRs (src0 of VOP2),
// 11 VALU instrs / 2 pairs, chains interleaved, abs as src modifiers.
#define DIST2S(MR, AXv, AYv, AZv, Y0X, Y0Y, Y0Z, Y1X, Y1Y, Y1Z)           \
  {                                                                        \
    float t0, t1, t2, t3, t4;                                              \
    asm("v_sub_f32 %1, %9, %6\n\t"                                         \
        "v_sub_f32 %2, %10, %7\n\t"                                        \
        "v_sub_f32 %3, %11, %8\n\t"                                        \
        "v_sub_f32 %4, %12, %6\n\t"                                        \
        "v_sub_f32 %5, %13, %7\n\t"                                        \
        "v_add_f32 %1, |%1|, |%2|\n\t"                                     \
        "v_sub_f32 %2, %14, %8\n\t"                                        \
        "v_add_f32 %4, |%4|, |%5|\n\t"                                     \
        "v_add_f32 %1, %1, |%3|\n\t"                                       \
        "v_add_f32 %4, %4, |%2|\n\t"                                       \
        "v_min3_f32 %0, %0, %1, %4"                                        \
        : "+v"(MR), "=&v"(t0), "=&v"(t1), "=&v"(t2), "=&v"(t3), "=&v"(t4)  \
        : "v"(AXv), "v"(AYv), "v"(AZv),                                    \
          "s"(Y0X), "s"(Y0Y), "s"(Y0Z), "s"(Y1X), "s"(Y1Y), "s"(Y1Z));    \
  }

// 8 y-points (one group) against this thread's single x-point
#define COMPUTE8(G16, G8)                                                  \
  {                                                                        \
    DIST2S(m0, ax, ay, az, G16[0], G16[1], G16[2], G16[3], G16[4], G16[5]); \
    DIST2S(m0, ax, ay, az, G16[6], G16[7], G16[8], G16[9], G16[10], G16[11]); \
    DIST2S(m0, ax, ay, az, G16[12], G16[13], G16[14], G16[15], G8[0], G8[1]); \
    DIST2S(m0, ax, ay, az, G8[2], G8[3], G8[4], G8[5], G8[6], G8[7]);      \
  }

__global__ __launch_bounds__(TPB, 8) void chamfer_kernel(
    const float* __restrict__ pc1, const float* __restrict__ flow,
    const float* __restrict__ pc2, unsigned* __restrict__ minbits,
    int N, int M) {
    const int t = threadIdx.x;

    // this thread's single x-point (coalesced 6-load prologue)
    const int i  = blockIdx.x * TPB + t;
    const int ic = (i < N) ? i : (N - 1);
    const float ax = pc1[3 * ic]     + flow[3 * ic];
    const float ay = pc1[3 * ic + 1] + flow[3 * ic + 1];
    const float az = pc1[3 * ic + 2] + flow[3 * ic + 2];

    float m0 = 3.0e38f;

    const int ybase = blockIdx.y * YSEG;
    const int yend  = (ybase + YSEG < M) ? (ybase + YSEG) : M;

    if (yend - ybase == YSEG) {
        const float* yp = pc2 + (size_t)3 * (size_t)ybase;
        sf16 A16, B16; sf8 A8, B8;
        SLOAD24(A16, A8, yp, "0", "64");           // group 0
#pragma unroll 1
        for (int it = 0; it < NITER; ++it) {
            SWAIT(A16, A8);                        // group 2it ready
            SLOAD24(B16, B8, yp, "96", "160");     // prefetch group 2it+1
            COMPUTE8(A16, A8);                     // 44 VALU instrs
            SWAIT(B16, B8);
            if (it + 1 < NITER)
                SLOAD24(A16, A8, yp, "192", "256");// prefetch group 2it+2
            COMPUTE8(B16, B8);
            yp += 48;
        }
    } else {
        // generic tail path (not hit for M % YSEG == 0)
        for (int j = ybase; j < yend; ++j) {
            const float yx = pc2[3 * j], yy = pc2[3 * j + 1], yz = pc2[3 * j + 2];
            m0 = fminf(m0, fabsf(ax - yx) + fabsf(ay - yy) + fabsf(az - yz));
        }
    }

    // exact, order-independent combine: uint order == float order for nonneg
    if (i < N) atomicMin(&minbits[i], __float_as_uint(m0));
}

// zeros for out[1..] (parallel across blocks); block 0 sums minbits -> out[0]
__global__ __launch_bounds__(TPB) void finalize_kernel(
    const unsigned* __restrict__ minbits, float* __restrict__ out,
    int N, int out_size, float invN) {
    const int t = threadIdx.x;
    const int stride = gridDim.x * TPB;
    for (int k = blockIdx.x * TPB + t; 1 + k < out_size; k += stride)
        out[1 + k] = 0.0f;

    if (blockIdx.x == 0) {
        float s = 0.0f;
        const uint4* p4 = (const uint4*)minbits;
        const int n4 = N >> 2;
        for (int k = t; k < n4; k += TPB) {
            uint4 v = p4[k];
            s += __uint_as_float(v.x) + __uint_as_float(v.y) +
                 __uint_as_float(v.z) + __uint_as_float(v.w);
        }
        for (int k = (n4 << 2) + t; k < N; k += TPB)
            s += __uint_as_float(minbits[k]);
#pragma unroll
        for (int off = 32; off > 0; off >>= 1) s += __shfl_down(s, off, 64);
        __shared__ float ls[TPB / 64];
        const int wid = t >> 6, lane = t & 63;
        if (lane == 0) ls[wid] = s;
        __syncthreads();
        if (t == 0) {
            float tot = 0.0f;
            for (int w = 0; w < TPB / 64; ++w) tot += ls[w];
            out[0] = tot * invN;
        }
    }
}

extern "C" void kernel_launch(void* const* d_in, const int* in_sizes, int n_in,
                              void* d_out, int out_size, void* d_ws, size_t ws_size,
                              hipStream_t stream) {
    const float* pc1  = (const float*)d_in[0];
    const float* flow = (const float*)d_in[1];
    const float* pc2  = (const float*)d_in[2];
    float* out = (float*)d_out;

    const int N = in_sizes[0] / 3;
    const int M = in_sizes[2] / 3;

    unsigned* minbits = (unsigned*)d_ws;

    // 0x7F7F7F7F = 3.39e38f sentinel; uint order == float order for nonneg
    hipMemsetAsync(minbits, 0x7F, (size_t)N * sizeof(unsigned), stream);

    const int nbN    = (N + TPB - 1) / TPB;       // 64
    const int msplit = (M + YSEG - 1) / YSEG;     // 32 -> grid 2048, 8 blocks/CU
    const int nbF    = (out_size - 1 + TPB - 1) / TPB;  // 64

    chamfer_kernel<<<dim3(nbN, msplit), TPB, 0, stream>>>(pc1, flow, pc2, minbits, N, M);
    finalize_kernel<<<nbF, TPB, 0, stream>>>(minbits, out, N, out_size, 1.0f / (float)N);
}

// Round 12
// 43.913 us; speedup vs baseline: 1.0014x; 1.0014x over previous
//
#include <hip/hip_runtime.h>

// One-way Chamfer (L1, K=1): out[0] = mean_i min_j ||x_i - y_j||_1 ; out[1..N] = 0
// N = M = 16384, D = 3, fp32.
//
// R12: confound resolution. R11 regressed chamfer to ~41us after changing
// BOTH RB (2->1) and combine (stores->atomicMin). Theory: RB=1 was the
// culprit (per-CU scalar-cache demand doubled to ~35 B/cyc, single-chain
// min3 serialization), not the 512K atomics (R9: 4.2M atomics ~ 3us).
// This round: R10's proven chamfer EXACTLY (RB=2, YSEG=256, grid 32x64,
// s_load_dwordx16/x8 double-buffered scalar broadcast, 11 VALU / 2 pairs)
// with only the combine swapped to atomicMin + fused finalize (zeros + sum
// in one kernel). Drops the 4MB partial round-trip and one dispatch.

#define TPB 256
#define RB 2
#define PTS_PER_BLOCK (TPB * RB)   // 512
#define YSEG 256                   // y-points per block = 32 groups of 8
#define NITER (YSEG / 16)          // unroll-2 loop iterations (16)

typedef float sf16 __attribute__((ext_vector_type(16)));
typedef float sf8  __attribute__((ext_vector_type(8)));

// issue the 24-dword (8 y-point) group load; byte offsets are string literals
#define SLOAD24(B16, B8, PTR, O16, O8)                                     \
  asm volatile("s_load_dwordx16 %0, %2, " O16 "\n\t"                       \
               "s_load_dwordx8  %1, %2, " O8                               \
               : "=s"(B16), "=s"(B8) : "s"(PTR));

// wait for ALL outstanding SMEM; "+s" makes consumers of the buffers
// data-dependent on this asm so reads can't be hoisted above the wait
#define SWAIT(B16, B8)                                                     \
  asm volatile("s_waitcnt lgkmcnt(0)" : "+s"(B16), "+s"(B8));

// MR = min3(MR, |a-y0|_1, |a-y1|_1); y components are SGPRs (src0 of VOP2),
// 11 VALU instrs / 2 pairs, chains interleaved, abs as src modifiers.
#define DIST2S(MR, AXv, AYv, AZv, Y0X, Y0Y, Y0Z, Y1X, Y1Y, Y1Z)           \
  {                                                                        \
    float t0, t1, t2, t3, t4;                                              \
    asm("v_sub_f32 %1, %9, %6\n\t"                                         \
        "v_sub_f32 %2, %10, %7\n\t"                                        \
        "v_sub_f32 %3, %11, %8\n\t"                                        \
        "v_sub_f32 %4, %12, %6\n\t"                                        \
        "v_sub_f32 %5, %13, %7\n\t"                                        \
        "v_add_f32 %1, |%1|, |%2|\n\t"                                     \
        "v_sub_f32 %2, %14, %8\n\t"                                        \
        "v_add_f32 %4, |%4|, |%5|\n\t"                                     \
        "v_add_f32 %1, %1, |%3|\n\t"                                       \
        "v_add_f32 %4, %4, |%2|\n\t"                                       \
        "v_min3_f32 %0, %0, %1, %4"                                        \
        : "+v"(MR), "=&v"(t0), "=&v"(t1), "=&v"(t2), "=&v"(t3), "=&v"(t4)  \
        : "v"(AXv), "v"(AYv), "v"(AZv),                                    \
          "s"(Y0X), "s"(Y0Y), "s"(Y0Z), "s"(Y1X), "s"(Y1Y), "s"(Y1Z));    \
  }

// 8 y-points (one group) x RB x-points
#define COMPUTE8(G16, G8)                                                  \
  {                                                                        \
    _Pragma("unroll")                                                      \
    for (int r = 0; r < RB; ++r)                                           \
      DIST2S(m[r], ax[r], ay[r], az[r],                                    \
             G16[0], G16[1], G16[2], G16[3], G16[4], G16[5]);              \
    _Pragma("unroll")                                                      \
    for (int r = 0; r < RB; ++r)                                           \
      DIST2S(m[r], ax[r], ay[r], az[r],                                    \
             G16[6], G16[7], G16[8], G16[9], G16[10], G16[11]);            \
    _Pragma("unroll")                                                      \
    for (int r = 0; r < RB; ++r)                                           \
      DIST2S(m[r], ax[r], ay[r], az[r],                                    \
             G16[12], G16[13], G16[14], G16[15], G8[0], G8[1]);            \
    _Pragma("unroll")                                                      \
    for (int r = 0; r < RB; ++r)                                           \
      DIST2S(m[r], ax[r], ay[r], az[r],                                    \
             G8[2], G8[3], G8[4], G8[5], G8[6], G8[7]);                    \
  }

__global__ __launch_bounds__(TPB, 8) void chamfer_kernel(
    const float* __restrict__ pc1, const float* __restrict__ flow,
    const float* __restrict__ pc2, unsigned* __restrict__ minbits,
    int N, int M) {
    const int t = threadIdx.x;

    // load + deform this thread's 2 x-points (stride TPB for coalescing)
    const int ibase = blockIdx.x * PTS_PER_BLOCK + t;
    float ax[RB], ay[RB], az[RB];
#pragma unroll
    for (int r = 0; r < RB; ++r) {
        const int i = ibase + r * TPB;
        const int ic = (i < N) ? i : (N - 1);
        ax[r] = pc1[3 * ic]     + flow[3 * ic];
        ay[r] = pc1[3 * ic + 1] + flow[3 * ic + 1];
        az[r] = pc1[3 * ic + 2] + flow[3 * ic + 2];
    }

    float m[RB];
#pragma unroll
    for (int r = 0; r < RB; ++r) m[r] = 3.0e38f;

    const int ybase = blockIdx.y * YSEG;
    const int yend  = (ybase + YSEG < M) ? (ybase + YSEG) : M;

    if (yend - ybase == YSEG) {
        const float* yp = pc2 + (size_t)3 * (size_t)ybase;
        sf16 A16, B16; sf8 A8, B8;
        SLOAD24(A16, A8, yp, "0", "64");           // group 0
#pragma unroll 1
        for (int it = 0; it < NITER; ++it) {
            SWAIT(A16, A8);                        // group 2it ready
            SLOAD24(B16, B8, yp, "96", "160");     // prefetch group 2it+1
            COMPUTE8(A16, A8);                     // 88 VALU instrs
            SWAIT(B16, B8);
            if (it + 1 < NITER)
                SLOAD24(A16, A8, yp, "192", "256");// prefetch group 2it+2
            COMPUTE8(B16, B8);
            yp += 48;
        }
    } else {
        // generic tail path (not hit for M % YSEG == 0)
        for (int j = ybase; j < yend; ++j) {
            const float yx = pc2[3 * j], yy = pc2[3 * j + 1], yz = pc2[3 * j + 2];
#pragma unroll
            for (int r = 0; r < RB; ++r)
                m[r] = fminf(m[r], fabsf(ax[r] - yx) + fabsf(ay[r] - yy) + fabsf(az[r] - yz));
        }
    }

    // exact, order-independent combine: uint order == float order for nonneg
#pragma unroll
    for (int r = 0; r < RB; ++r) {
        const int i = ibase + r * TPB;
        if (i < N) atomicMin(&minbits[i], __float_as_uint(m[r]));
    }
}

// zeros for out[1..] (parallel across blocks); block 0 sums minbits -> out[0]
__global__ __launch_bounds__(TPB) void finalize_kernel(
    const unsigned* __restrict__ minbits, float* __restrict__ out,
    int N, int out_size, float invN) {
    const int t = threadIdx.x;
    const int stride = gridDim.x * TPB;
    for (int k = blockIdx.x * TPB + t; 1 + k < out_size; k += stride)
        out[1 + k] = 0.0f;

    if (blockIdx.x == 0) {
        float s = 0.0f;
        const uint4* p4 = (const uint4*)minbits;
        const int n4 = N >> 2;
        for (int k = t; k < n4; k += TPB) {
            uint4 v = p4[k];
            s += __uint_as_float(v.x) + __uint_as_float(v.y) +
                 __uint_as_float(v.z) + __uint_as_float(v.w);
        }
        for (int k = (n4 << 2) + t; k < N; k += TPB)
            s += __uint_as_float(minbits[k]);
#pragma unroll
        for (int off = 32; off > 0; off >>= 1) s += __shfl_down(s, off, 64);
        __shared__ float ls[TPB / 64];
        const int wid = t >> 6, lane = t & 63;
        if (lane == 0) ls[wid] = s;
        __syncthreads();
        if (t == 0) {
            float tot = 0.0f;
            for (int w = 0; w < TPB / 64; ++w) tot += ls[w];
            out[0] = tot * invN;
        }
    }
}

extern "C" void kernel_launch(void* const* d_in, const int* in_sizes, int n_in,
                              void* d_out, int out_size, void* d_ws, size_t ws_size,
                              hipStream_t stream) {
    const float* pc1  = (const float*)d_in[0];
    const float* flow = (const float*)d_in[1];
    const float* pc2  = (const float*)d_in[2];
    float* out = (float*)d_out;

    const int N = in_sizes[0] / 3;
    const int M = in_sizes[2] / 3;

    unsigned* minbits = (unsigned*)d_ws;

    // 0x7F7F7F7F = 3.39e38f sentinel; uint order == float order for nonneg
    hipMemsetAsync(minbits, 0x7F, (size_t)N * sizeof(unsigned), stream);

    const int nbN    = (N + PTS_PER_BLOCK - 1) / PTS_PER_BLOCK;  // 32
    const int msplit = (M + YSEG - 1) / YSEG;                    // 64 -> grid 2048
    const int nbF    = (out_size + TPB - 2) / TPB;               // 64

    chamfer_kernel<<<dim3(nbN, msplit), TPB, 0, stream>>>(pc1, flow, pc2, minbits, N, M);
    finalize_kernel<<<nbF, TPB, 0, stream>>>(minbits, out, N, out_size, 1.0f / (float)N);
}